// Round 3
// baseline (624.279 us; speedup 1.0000x reference)
//
#include <hip/hip_runtime.h>
#include <hip/hip_bf16.h>

typedef __attribute__((ext_vector_type(8))) short short8;
typedef __attribute__((ext_vector_type(4))) float floatx4;

#define NRES 700
#define DDIM 1024
#define HID 1024
// M = 89600, K = 1024, N = 1024. BK = 32, 32 K-steps.

__device__ __forceinline__ unsigned short f2bf(float f) {
  unsigned u = __float_as_uint(f);
  u = (u + 0x7FFFu + ((u >> 16) & 1u)) >> 16;  // RNE
  return (unsigned short)u;
}

__device__ __forceinline__ void async_copy16(void* lds, const void* g) {
  __builtin_amdgcn_global_load_lds(
      (const __attribute__((address_space(1))) unsigned*)g,
      (__attribute__((address_space(3))) unsigned*)lds, 16, 0, 0);
}

__device__ __forceinline__ short bfbits(float x) {
  __hip_bfloat16 h = __float2bfloat16(x);  // compiler emits v_cvt_pk_bf16_f32 pairs
  return *reinterpret_cast<short*>(&h);
}

// W1 [d][h] fp32 -> W1T [h][d] bf16
__global__ void transpose_w1_kernel(const float* __restrict__ W1,
                                    unsigned short* __restrict__ W1T) {
  __shared__ float tile[32][33];
  int bx = blockIdx.x, by = blockIdx.y;
  int tx = threadIdx.x, ty = threadIdx.y;
#pragma unroll
  for (int i = 0; i < 32; i += 8)
    tile[ty + i][tx] = W1[(size_t)(by * 32 + ty + i) * HID + bx * 32 + tx];
  __syncthreads();
#pragma unroll
  for (int i = 0; i < 32; i += 8)
    W1T[(size_t)(bx * 32 + ty + i) * DDIM + by * 32 + tx] = f2bf(tile[tx][ty + i]);
}

__global__ void init_out_kernel(float* __restrict__ out, const float* __restrict__ b2, int n) {
  int i = blockIdx.x * blockDim.x + threadIdx.x;
  if (i < n) out[i] = b2[0];
}

// Fused: h = relu(A@W1 + b1); y = h@W2 (atomic accumulate into b2-initialized out).
// 128x128 tile, BK=32, 4 waves (2x2), double-buffered:
//   A: fp32 via global_load_lds (linear dest + inverse-swizzled source), cvt on read
//   B: bf16 reg-staged into padded [128][40] LDS
__launch_bounds__(256, 3)
__global__ void fused_mlp_kernel(const float* __restrict__ A,
                                 const unsigned short* __restrict__ W1T,
                                 const float* __restrict__ b1,
                                 const float* __restrict__ W2,
                                 float* __restrict__ out) {
  __shared__ __align__(16) float As[2][128 * 32];           // 32 KB, XOR-swizzled 16B chunks
  __shared__ __align__(16) unsigned short Bs[2][128 * 40];  // 20 KB, padded rows (40 shorts)

  int bid = blockIdx.x;
  // bijective XCD swizzle: 5600 = 8 * 700
  int w = (bid & 7) * 700 + (bid >> 3);
  int blk_m = w >> 3;  // residue r: 0..699
  int blk_n = w & 7;   // 0..7
  int m0 = blk_m * 128;
  int n0 = blk_n * 128;

  int t = threadIdx.x;
  int lane = t & 63;
  int wid = t >> 6;
  int wm = wid >> 1, wn = wid & 1;       // 2x2 waves, 64x64 each
  int lrow = lane & 15, lk = lane >> 4;  // fragment decomposition

  floatx4 acc[4][4];
#pragma unroll
  for (int i = 0; i < 4; ++i)
#pragma unroll
    for (int j = 0; j < 4; ++j) acc[i][j] = (floatx4)(0.f);

  int4 breg[2];

  // ---- staging: issue loads for K-tile kt into buffer buf ----
  auto stage_issue = [&](int buf, int kt) {
    int k0 = kt * 32;
    // B -> regs (2 x int4); W1T is L2-resident (2 MB)
#pragma unroll
    for (int p = 0; p < 2; ++p) {
      int row = p * 64 + (t >> 2), c = t & 3;
      breg[p] = *(const int4*)(W1T + (size_t)(n0 + row) * DDIM + k0 + c * 8);
    }
    // A -> LDS via DMA. Linear dest slot d -> (row=d>>3, slot=d&7); source chunk = slot^(row&7).
#pragma unroll
    for (int p = 0; p < 4; ++p) {
      int d = (wid * 4 + p) * 64 + lane;
      int row = d >> 3, slot = d & 7;
      int c = slot ^ (row & 7);
      async_copy16(&As[buf][(wid * 4 + p) * 256],
                   A + (size_t)(m0 + row) * DDIM + k0 + c * 4);
    }
  };
  auto stage_write_b = [&](int buf) {
#pragma unroll
    for (int p = 0; p < 2; ++p) {
      int row = p * 64 + (t >> 2), c = t & 3;
      *(int4*)(&Bs[buf][row * 40 + c * 8]) = breg[p];
    }
  };

  // ---- compute one K-tile from buffer buf ----
  auto compute = [&](int buf) {
    short8 af[4], bf[4];
#pragma unroll
    for (int f = 0; f < 4; ++f) {
      int ar = wm * 64 + f * 16 + lrow;
      int s0 = (2 * lk) ^ (ar & 7);
      const float* ap = &As[buf][ar * 32];
      float4 f0 = *(const float4*)(ap + s0 * 4);
      float4 f1 = *(const float4*)(ap + (s0 ^ 1) * 4);
      short8 v;
      v[0] = bfbits(f0.x); v[1] = bfbits(f0.y); v[2] = bfbits(f0.z); v[3] = bfbits(f0.w);
      v[4] = bfbits(f1.x); v[5] = bfbits(f1.y); v[6] = bfbits(f1.z); v[7] = bfbits(f1.w);
      af[f] = v;
      int br = wn * 64 + f * 16 + lrow;
      bf[f] = *(const short8*)(&Bs[buf][br * 40 + lk * 8]);
    }
#pragma unroll
    for (int fm = 0; fm < 4; ++fm)
#pragma unroll
      for (int fn = 0; fn < 4; ++fn)
        acc[fm][fn] = __builtin_amdgcn_mfma_f32_16x16x32_bf16(af[fm], bf[fn], acc[fm][fn], 0, 0, 0);
  };

  // ---- 2-phase double-buffered main loop ----
  stage_issue(0, 0);
  stage_write_b(0);  // compiler waits vmcnt for breg deps
  __syncthreads();   // drains global_load_lds + ds_write

  int cur = 0;
  for (int kt = 0; kt < 31; ++kt) {
    stage_issue(cur ^ 1, kt + 1);  // prefetch next tile (DMA + reg loads in flight)
    compute(cur);                  // MFMA on current tile hides the latency
    stage_write_b(cur ^ 1);        // land B after compute
    __syncthreads();
    cur ^= 1;
  }
  compute(cur);  // tail tile

  // ---- epilogue: +b1, relu, dot W2, shfl-reduce 16 cols, atomicAdd ----
  float w2v[4], b1v[4];
#pragma unroll
  for (int fn = 0; fn < 4; ++fn) {
    int col = n0 + wn * 64 + fn * 16 + lrow;
    w2v[fn] = W2[col];
    b1v[fn] = b1[col];
  }
#pragma unroll
  for (int fm = 0; fm < 4; ++fm) {
#pragma unroll
    for (int j = 0; j < 4; ++j) {
      float p = 0.f;
#pragma unroll
      for (int fn = 0; fn < 4; ++fn) {
        float h = acc[fm][fn][j] + b1v[fn];
        h = fmaxf(h, 0.f);
        p += h * w2v[fn];
      }
      p += __shfl_xor(p, 1);
      p += __shfl_xor(p, 2);
      p += __shfl_xor(p, 4);
      p += __shfl_xor(p, 8);
      if ((lane & 15) == 0) {
        int row = wm * 64 + fm * 16 + (lk << 2) + j;  // local row = batch b
        atomicAdd(&out[row * NRES + blk_m], p);       // out[b*700 + r]
      }
    }
  }
}

extern "C" void kernel_launch(void* const* d_in, const int* in_sizes, int n_in,
                              void* d_out, int out_size, void* d_ws, size_t ws_size,
                              hipStream_t stream) {
  const float* s_s = (const float*)d_in[0];  // [700,128,1024] fp32
  const float* W1 = (const float*)d_in[1];   // [1024,1024]
  const float* b1 = (const float*)d_in[2];   // [1024]
  const float* W2 = (const float*)d_in[3];   // [1024,1]
  const float* b2 = (const float*)d_in[4];   // [1]
  float* out = (float*)d_out;                // [128,700,1] fp32

  unsigned short* W1T = (unsigned short*)d_ws;  // 2 MB bf16

  dim3 tb(32, 8);
  dim3 tg(HID / 32, DDIM / 32);
  transpose_w1_kernel<<<tg, tb, 0, stream>>>(W1, W1T);

  init_out_kernel<<<(out_size + 255) / 256, 256, 0, stream>>>(out, b2, out_size);

  fused_mlp_kernel<<<NRES * 8, 256, 0, stream>>>(s_s, W1T, b1, W2, out);
}

// Round 4
// 302.287 us; speedup vs baseline: 2.0652x; 2.0652x over previous
//
#include <hip/hip_runtime.h>
#include <hip/hip_bf16.h>

typedef __attribute__((ext_vector_type(8))) short short8;
typedef __attribute__((ext_vector_type(4))) float floatx4;

#define NRES 700
#define DDIM 1024
#define HID 1024
// M = 89600, K = 1024, N = 1024

__device__ __forceinline__ unsigned short f2bf(float f) {
  unsigned u = __float_as_uint(f);
  u = (u + 0x7FFFu + ((u >> 16) & 1u)) >> 16;  // RNE
  return (unsigned short)u;
}

__device__ __forceinline__ void async_copy16(void* lds, const void* g) {
  __builtin_amdgcn_global_load_lds(
      (const __attribute__((address_space(1))) unsigned*)g,
      (__attribute__((address_space(3))) unsigned*)lds, 16, 0, 0);
}

// ---- prepass: A fp32 -> bf16 (streaming, memory-bound) ----
__global__ void convert_a_kernel(const float* __restrict__ A,
                                 unsigned short* __restrict__ Abf, long n8) {
  long i = (long)blockIdx.x * blockDim.x + threadIdx.x;
  long stride = (long)gridDim.x * blockDim.x;
  for (; i < n8; i += stride) {
    const float* p = A + i * 8;
    float4 f0 = *(const float4*)p;
    float4 f1 = *(const float4*)(p + 4);
    int4 pk;
    pk.x = f2bf(f0.x) | ((unsigned)f2bf(f0.y) << 16);
    pk.y = f2bf(f0.z) | ((unsigned)f2bf(f0.w) << 16);
    pk.z = f2bf(f1.x) | ((unsigned)f2bf(f1.y) << 16);
    pk.w = f2bf(f1.z) | ((unsigned)f2bf(f1.w) << 16);
    *(int4*)(Abf + i * 8) = pk;
  }
}

// W1 [d][h] fp32 -> W1T [h][d] bf16
__global__ void transpose_w1_kernel(const float* __restrict__ W1,
                                    unsigned short* __restrict__ W1T) {
  __shared__ float tile[32][33];
  int bx = blockIdx.x, by = blockIdx.y;
  int tx = threadIdx.x, ty = threadIdx.y;
#pragma unroll
  for (int i = 0; i < 32; i += 8)
    tile[ty + i][tx] = W1[(size_t)(by * 32 + ty + i) * HID + bx * 32 + tx];
  __syncthreads();
#pragma unroll
  for (int i = 0; i < 32; i += 8)
    W1T[(size_t)(bx * 32 + ty + i) * DDIM + by * 32 + tx] = f2bf(tile[tx][ty + i]);
}

__global__ void init_out_kernel(float* __restrict__ out, const float* __restrict__ b2, int n) {
  int i = blockIdx.x * blockDim.x + threadIdx.x;
  if (i < n) out[i] = b2[0];
}

// ---- main: m97-structure GEMM, both tiles bf16 via global_load_lds ----
// 128x128 tile, BK=64, 4 waves (2x2). LDS linear dest + inverse-swizzled
// source (involution: chunk ^= row&7 on 16B chunks of 128B rows), XOR on read.
__launch_bounds__(256, 2)
__global__ void fused_mlp_kernel(const unsigned short* __restrict__ Abf,
                                 const unsigned short* __restrict__ W1T,
                                 const float* __restrict__ b1,
                                 const float* __restrict__ W2,
                                 float* __restrict__ out) {
  __shared__ __align__(16) unsigned short As[128 * 64];  // 16 KB
  __shared__ __align__(16) unsigned short Bs[128 * 64];  // 16 KB

  int bid = blockIdx.x;
  // bijective XCD swizzle: 5600 = 8 XCDs * 700
  int w = (bid & 7) * 700 + (bid >> 3);
  int blk_m = w >> 3;  // residue r: 0..699
  int blk_n = w & 7;   // 0..7
  int m0 = blk_m * 128;
  int n0 = blk_n * 128;

  int t = threadIdx.x;
  int lane = t & 63;
  int wid = t >> 6;
  int wm = wid >> 1, wn = wid & 1;       // 2x2 waves, 64x64 each
  int lrow = lane & 15, lk = lane >> 4;  // fragment decomposition

  floatx4 acc[4][4];
#pragma unroll
  for (int i = 0; i < 4; ++i)
#pragma unroll
    for (int j = 0; j < 4; ++j) acc[i][j] = (floatx4)(0.f);

  for (int kt = 0; kt < 16; ++kt) {
    int k0 = kt * 64;
    // ---- stage: 4 DMA copies per matrix per thread, no reg round-trip ----
#pragma unroll
    for (int i = 0; i < 4; ++i) {
      int base_chunk = i * 256 + wid * 64;  // wave-uniform LDS base (16B chunks)
      int c = base_chunk + lane;            // this lane's chunk
      int row = c >> 3, slot = c & 7;
      int sc = slot ^ (row & 7);            // inverse-swizzled source chunk
      async_copy16(&As[base_chunk * 8], Abf + (size_t)(m0 + row) * DDIM + k0 + sc * 8);
      async_copy16(&Bs[base_chunk * 8], W1T + (size_t)(n0 + row) * DDIM + k0 + sc * 8);
    }
    __syncthreads();  // compiler emits vmcnt(0) drain before s_barrier

    // ---- compute: 2 k-slices of 32, 16 MFMA each ----
#pragma unroll
    for (int ks = 0; ks < 2; ++ks) {
      short8 af[4], bf[4];
#pragma unroll
      for (int f = 0; f < 4; ++f) {
        int arow = wm * 64 + f * 16 + lrow;
        int ac = (ks * 4 + lk) ^ (arow & 7);
        af[f] = *(const short8*)(&As[arow * 64 + ac * 8]);
        int brow = wn * 64 + f * 16 + lrow;
        int bc = (ks * 4 + lk) ^ (brow & 7);
        bf[f] = *(const short8*)(&Bs[brow * 64 + bc * 8]);
      }
#pragma unroll
      for (int fm = 0; fm < 4; ++fm)
#pragma unroll
        for (int fn = 0; fn < 4; ++fn)
          acc[fm][fn] = __builtin_amdgcn_mfma_f32_16x16x32_bf16(af[fm], bf[fn], acc[fm][fn], 0, 0, 0);
    }
    __syncthreads();  // protect LDS before next stage
  }

  // ---- epilogue: +b1, relu, dot W2, shfl-reduce 16 cols, atomicAdd ----
  float w2v[4], b1v[4];
#pragma unroll
  for (int fn = 0; fn < 4; ++fn) {
    int col = n0 + wn * 64 + fn * 16 + lrow;
    w2v[fn] = W2[col];
    b1v[fn] = b1[col];
  }
#pragma unroll
  for (int fm = 0; fm < 4; ++fm) {
#pragma unroll
    for (int j = 0; j < 4; ++j) {
      float p = 0.f;
#pragma unroll
      for (int fn = 0; fn < 4; ++fn) {
        float h = acc[fm][fn][j] + b1v[fn];
        h = fmaxf(h, 0.f);
        p += h * w2v[fn];
      }
      p += __shfl_xor(p, 1);
      p += __shfl_xor(p, 2);
      p += __shfl_xor(p, 4);
      p += __shfl_xor(p, 8);
      if ((lane & 15) == 0) {
        int row = wm * 64 + fm * 16 + (lk << 2) + j;  // local row = batch b
        atomicAdd(&out[row * NRES + blk_m], p);       // out[b*700 + r]
      }
    }
  }
}

// ---- fallback (round-2 kernel, proven 435 us): used if ws_size too small ----
__launch_bounds__(256, 2)
__global__ void fused_mlp_fallback(const float* __restrict__ A,
                                   const unsigned short* __restrict__ W1T,
                                   const float* __restrict__ b1,
                                   const float* __restrict__ W2,
                                   float* __restrict__ out) {
  __shared__ unsigned short As[128 * 64];
  __shared__ unsigned short Bs[128 * 64];
  int bid = blockIdx.x;
  int w = (bid & 7) * 700 + (bid >> 3);
  int blk_m = w >> 3, blk_n = w & 7;
  int m0 = blk_m * 128, n0 = blk_n * 128;
  int t = threadIdx.x, lane = t & 63, wid = t >> 6;
  int wm = wid >> 1, wn = wid & 1;
  int lrow = lane & 15, lk = lane >> 4;
  floatx4 acc[4][4];
#pragma unroll
  for (int i = 0; i < 4; ++i)
#pragma unroll
    for (int j = 0; j < 4; ++j) acc[i][j] = (floatx4)(0.f);
  for (int kt = 0; kt < 16; ++kt) {
    int k0 = kt * 64;
#pragma unroll
    for (int i = 0; i < 4; ++i) {
      int c = i * 256 + t;
      int row = c >> 3, c8 = c & 7;
      int dst = row * 64 + ((c8 ^ (row & 7)) * 8);
      const float* gp = A + (size_t)(m0 + row) * DDIM + k0 + c8 * 8;
      float4 f0 = *(const float4*)gp;
      float4 f1 = *(const float4*)(gp + 4);
      int4 pk;
      pk.x = f2bf(f0.x) | ((unsigned)f2bf(f0.y) << 16);
      pk.y = f2bf(f0.z) | ((unsigned)f2bf(f0.w) << 16);
      pk.z = f2bf(f1.x) | ((unsigned)f2bf(f1.y) << 16);
      pk.w = f2bf(f1.z) | ((unsigned)f2bf(f1.w) << 16);
      *(int4*)(&As[dst]) = pk;
      const unsigned short* gb = W1T + (size_t)(n0 + row) * DDIM + k0 + c8 * 8;
      *(int4*)(&Bs[dst]) = *(const int4*)gb;
    }
    __syncthreads();
#pragma unroll
    for (int ks = 0; ks < 2; ++ks) {
      short8 af[4], bf[4];
#pragma unroll
      for (int f = 0; f < 4; ++f) {
        int arow = wm * 64 + f * 16 + lrow;
        int ac = (ks * 4 + lk) ^ (arow & 7);
        af[f] = *(const short8*)(&As[arow * 64 + ac * 8]);
        int brow = wn * 64 + f * 16 + lrow;
        int bc = (ks * 4 + lk) ^ (brow & 7);
        bf[f] = *(const short8*)(&Bs[brow * 64 + bc * 8]);
      }
#pragma unroll
      for (int fm = 0; fm < 4; ++fm)
#pragma unroll
        for (int fn = 0; fn < 4; ++fn)
          acc[fm][fn] = __builtin_amdgcn_mfma_f32_16x16x32_bf16(af[fm], bf[fn], acc[fm][fn], 0, 0, 0);
    }
    __syncthreads();
  }
  float w2v[4], b1v[4];
#pragma unroll
  for (int fn = 0; fn < 4; ++fn) {
    int col = n0 + wn * 64 + fn * 16 + lrow;
    w2v[fn] = W2[col];
    b1v[fn] = b1[col];
  }
#pragma unroll
  for (int fm = 0; fm < 4; ++fm) {
#pragma unroll
    for (int j = 0; j < 4; ++j) {
      float p = 0.f;
#pragma unroll
      for (int fn = 0; fn < 4; ++fn) {
        float h = acc[fm][fn][j] + b1v[fn];
        h = fmaxf(h, 0.f);
        p += h * w2v[fn];
      }
      p += __shfl_xor(p, 1);
      p += __shfl_xor(p, 2);
      p += __shfl_xor(p, 4);
      p += __shfl_xor(p, 8);
      if ((lane & 15) == 0) {
        int row = wm * 64 + fm * 16 + (lk << 2) + j;
        atomicAdd(&out[row * NRES + blk_m], p);
      }
    }
  }
}

extern "C" void kernel_launch(void* const* d_in, const int* in_sizes, int n_in,
                              void* d_out, int out_size, void* d_ws, size_t ws_size,
                              hipStream_t stream) {
  const float* s_s = (const float*)d_in[0];  // [700,128,1024] fp32
  const float* W1 = (const float*)d_in[1];   // [1024,1024]
  const float* b1 = (const float*)d_in[2];   // [1024]
  const float* W2 = (const float*)d_in[3];   // [1024,1]
  const float* b2 = (const float*)d_in[4];   // [1]
  float* out = (float*)d_out;                // [128,700,1] fp32

  unsigned short* W1T = (unsigned short*)d_ws;  // 2 MB bf16
  const size_t w1t_bytes = (size_t)HID * DDIM * 2;
  const size_t abf_bytes = (size_t)NRES * 128 * DDIM * 2;  // 183.5 MB

  dim3 tb(32, 8);
  dim3 tg(HID / 32, DDIM / 32);
  transpose_w1_kernel<<<tg, tb, 0, stream>>>(W1, W1T);

  init_out_kernel<<<(out_size + 255) / 256, 256, 0, stream>>>(out, b2, out_size);

  if (ws_size >= w1t_bytes + abf_bytes) {
    unsigned short* Abf = (unsigned short*)((char*)d_ws + w1t_bytes);
    long n8 = (long)NRES * 128 * DDIM / 8;
    convert_a_kernel<<<2048, 256, 0, stream>>>(s_s, Abf, n8);
    fused_mlp_kernel<<<NRES * 8, 256, 0, stream>>>(Abf, W1T, b1, W2, out);
  } else {
    fused_mlp_fallback<<<NRES * 8, 256, 0, stream>>>(s_s, W1T, b1, W2, out);
  }
}